// Round 1
// baseline (77.801 us; speedup 1.0000x reference)
//
#include <hip/hip_runtime.h>

// O = U X U^H with U = kron of 11 single-qubit gates (2048^2, complex64).
// Exploit kron structure: U@v = 11 radix-2 butterfly stages (strides 1..1024).
// Pipeline: K1 (col-transform bits0-4, LDS tiles) -> K2 (col bits5-10, LDS,
// in-place) -> K3 (row-transform conj(U) fully in registers + shfl_xor),
// writes Re(O) (out_size==DIM*DIM) or interleaved complex (out_size==2*DIM*DIM).
// Traffic ~160 MB total, memory-bound.

#define DIM 2048
#define NQ 11

__device__ __forceinline__ float2 cmul(float2 a, float2 b) {
    return make_float2(a.x * b.x - a.y * b.y, a.x * b.y + a.y * b.x);
}

// Build per-qubit composite gates g = Rz @ Ry @ Rx, plus conjugates.
// Layout in gbuf: [q*4 + (2*r+c)] for g, [44 + q*4 + (2*r+c)] for conj(g).
__global__ void build_gates_kernel(const float* __restrict__ w,
                                   float2* __restrict__ gbuf) {
    int q = threadIdx.x;
    if (q >= NQ) return;
    const float WM = 0.632455532033675866f;  // GAIN * 5^-0.5 = sqrt(2/5)
    float hx = 0.5f * WM * w[q * 3 + 0];
    float hy = 0.5f * WM * w[q * 3 + 1];
    float hz = 0.5f * WM * w[q * 3 + 2];
    float cx, sx, cy, sy, cz, sz;
    sincosf(hx, &sx, &cx);
    sincosf(hy, &sy, &cy);
    sincosf(hz, &sz, &cz);
    // m = ry @ rx
    float2 m00 = make_float2(cy * cx,  sy * sx);
    float2 m01 = make_float2(-sy * cx, -cy * sx);
    float2 m10 = make_float2(sy * cx,  -cy * sx);
    float2 m11 = make_float2(cy * cx,  -sy * sx);
    float2 ez  = make_float2(cz, -sz);   // exp(-i hz)
    float2 ezc = make_float2(cz,  sz);
    float2 g00 = cmul(ez, m00);
    float2 g01 = cmul(ez, m01);
    float2 g10 = cmul(ezc, m10);
    float2 g11 = cmul(ezc, m11);
    gbuf[q * 4 + 0] = g00;
    gbuf[q * 4 + 1] = g01;
    gbuf[q * 4 + 2] = g10;
    gbuf[q * 4 + 3] = g11;
    gbuf[44 + q * 4 + 0] = make_float2(g00.x, -g00.y);
    gbuf[44 + q * 4 + 1] = make_float2(g01.x, -g01.y);
    gbuf[44 + q * 4 + 2] = make_float2(g10.x, -g10.y);
    gbuf[44 + q * 4 + 3] = make_float2(g11.x, -g11.y);
}

// K1: Y = (gates on row-index bits 0..4) applied to X columns.
// Tile: 32 consecutive rows x 64 cols. Row-index bit b -> qubit 10-b.
__global__ __launch_bounds__(256) void colgate_low(
    const float* __restrict__ X, float2* __restrict__ Y,
    const float2* __restrict__ g) {
    __shared__ float2 tile[32][64];
    int t = threadIdx.x;
    int r0 = (blockIdx.x >> 5) * 32;   // 64 row groups
    int c0 = (blockIdx.x & 31) * 64;   // 32 col groups
#pragma unroll
    for (int e = 0; e < 8; ++e) {
        int idx = t + e * 256;
        int r = idx >> 6, c = idx & 63;
        tile[r][c] = make_float2(X[(size_t)(r0 + r) * DIM + c0 + c], 0.f);
    }
    int c = t & 63, pg = t >> 6;
    for (int b = 0; b < 5; ++b) {
        int s = 1 << b;
        __syncthreads();
        int q = 10 - b;
        float2 g00 = g[q * 4 + 0], g01 = g[q * 4 + 1];
        float2 g10 = g[q * 4 + 2], g11 = g[q * 4 + 3];
        for (int pi = pg; pi < 16; pi += 4) {
            int k0 = ((pi >> b) << (b + 1)) | (pi & (s - 1));
            int k1 = k0 + s;
            float2 A = tile[k0][c], B = tile[k1][c];
            float2 n0 = cmul(g00, A), n1 = cmul(g10, A);
            float2 pb = cmul(g01, B), qb = cmul(g11, B);
            tile[k0][c] = make_float2(n0.x + pb.x, n0.y + pb.y);
            tile[k1][c] = make_float2(n1.x + qb.x, n1.y + qb.y);
        }
    }
    __syncthreads();
#pragma unroll
    for (int e = 0; e < 8; ++e) {
        int idx = t + e * 256;
        int r = idx >> 6, cc = idx & 63;
        Y[(size_t)(r0 + r) * DIM + c0 + cc] = tile[r][cc];
    }
}

// K2: gates on row-index bits 5..10, in-place on Y.
// Block: rows {cb + 32*m, m=0..63} x 64 cols. Row bit 5+b -> qubit 5-b.
__global__ __launch_bounds__(256) void colgate_high(
    float2* __restrict__ Y, const float2* __restrict__ g) {
    __shared__ float2 tile[64][64];
    int t = threadIdx.x;
    int cb = blockIdx.x >> 5;          // 0..31 (row bits 0..4)
    int c0 = (blockIdx.x & 31) * 64;
#pragma unroll
    for (int e = 0; e < 16; ++e) {
        int idx = t + e * 256;
        int m = idx >> 6, c = idx & 63;
        tile[m][c] = Y[(size_t)(cb + 32 * m) * DIM + c0 + c];
    }
    int c = t & 63, pg = t >> 6;
    for (int b = 0; b < 6; ++b) {
        int s = 1 << b;
        __syncthreads();
        int q = 5 - b;
        float2 g00 = g[q * 4 + 0], g01 = g[q * 4 + 1];
        float2 g10 = g[q * 4 + 2], g11 = g[q * 4 + 3];
        for (int pi = pg; pi < 32; pi += 4) {
            int k0 = ((pi >> b) << (b + 1)) | (pi & (s - 1));
            int k1 = k0 + s;
            float2 A = tile[k0][c], B = tile[k1][c];
            float2 n0 = cmul(g00, A), n1 = cmul(g10, A);
            float2 pb = cmul(g01, B), qb = cmul(g11, B);
            tile[k0][c] = make_float2(n0.x + pb.x, n0.y + pb.y);
            tile[k1][c] = make_float2(n1.x + qb.x, n1.y + qb.y);
        }
    }
    __syncthreads();
#pragma unroll
    for (int e = 0; e < 16; ++e) {
        int idx = t + e * 256;
        int m = idx >> 6, cc = idx & 63;
        Y[(size_t)(cb + 32 * m) * DIM + c0 + cc] = tile[m][cc];
    }
}

// K3: O[i,:] = conj(U) @ Y[i,:]. One wave per row; lane holds j = 64*r + lane
// for r=0..31 (32 complex in VGPRs). Col bits 0..5 -> shfl_xor across lanes
// (qubits 10..5); col bits 6..10 -> in-register strides 1..16 (qubits 4..0).
__global__ __launch_bounds__(256) void rowgate_final(
    const float2* __restrict__ Y, float* __restrict__ Out,
    const float2* __restrict__ gAll, int writeComplex) {
    const float2* g = gAll + 44;  // conjugated set
    int lane = threadIdx.x & 63;
    int row = blockIdx.x * 4 + (threadIdx.x >> 6);
    const float2* yrow = Y + (size_t)row * DIM;

    float2 v[32];
#pragma unroll
    for (int r = 0; r < 32; ++r) v[r] = yrow[64 * r + lane];

    // cross-lane gates: col bit b in 0..5, qubit 10-b
#pragma unroll
    for (int b = 0; b < 6; ++b) {
        int q = 10 - b;
        float2 g00 = g[q * 4 + 0], g01 = g[q * 4 + 1];
        float2 g10 = g[q * 4 + 2], g11 = g[q * 4 + 3];
        bool hi = (lane & (1 << b)) != 0;
#pragma unroll
        for (int r = 0; r < 32; ++r) {
            float2 pv;
            pv.x = __shfl_xor(v[r].x, 1 << b);
            pv.y = __shfl_xor(v[r].y, 1 << b);
            float2 a = hi ? pv : v[r];     // element with bit=0
            float2 bb = hi ? v[r] : pv;    // element with bit=1
            float2 lo0 = cmul(g00, a), lo1 = cmul(g01, bb);
            float2 hi0 = cmul(g10, a), hi1 = cmul(g11, bb);
            float2 nlo = make_float2(lo0.x + lo1.x, lo0.y + lo1.y);
            float2 nhi = make_float2(hi0.x + hi1.x, hi0.y + hi1.y);
            v[r] = hi ? nhi : nlo;
        }
    }
    // in-register gates: col bit 6+b -> r-stride 1<<b, qubit 4-b
#pragma unroll
    for (int b = 0; b < 5; ++b) {
        int s = 1 << b;
        int q = 4 - b;
        float2 g00 = g[q * 4 + 0], g01 = g[q * 4 + 1];
        float2 g10 = g[q * 4 + 2], g11 = g[q * 4 + 3];
#pragma unroll
        for (int k0 = 0; k0 < 32; ++k0) {
            if ((k0 & s) == 0) {
                int k1 = k0 + s;
                float2 A = v[k0], B = v[k1];
                float2 n0 = cmul(g00, A), p0 = cmul(g01, B);
                float2 n1 = cmul(g10, A), p1 = cmul(g11, B);
                v[k0] = make_float2(n0.x + p0.x, n0.y + p0.y);
                v[k1] = make_float2(n1.x + p1.x, n1.y + p1.y);
            }
        }
    }

    if (writeComplex) {
        float2* o2 = (float2*)Out;
#pragma unroll
        for (int r = 0; r < 32; ++r)
            o2[(size_t)row * DIM + 64 * r + lane] = v[r];
    } else {
#pragma unroll
        for (int r = 0; r < 32; ++r)
            Out[(size_t)row * DIM + 64 * r + lane] = v[r].x;
    }
}

extern "C" void kernel_launch(void* const* d_in, const int* in_sizes, int n_in,
                              void* d_out, int out_size, void* d_ws,
                              size_t ws_size, hipStream_t stream) {
    const float* X = (const float*)d_in[0];
    const float* wt = (const float*)d_in[1];
    float* out = (float*)d_out;

    float2* gates = (float2*)d_ws;                       // 88 float2 = 704 B
    float2* Y = (float2*)((char*)d_ws + 1024);           // DIM*DIM complex = 32 MB

    build_gates_kernel<<<1, 64, 0, stream>>>(wt, gates);
    colgate_low<<<2048, 256, 0, stream>>>(X, Y, gates);
    colgate_high<<<1024, 256, 0, stream>>>(Y, gates);
    int wc = (out_size >= 2 * DIM * DIM) ? 1 : 0;
    rowgate_final<<<512, 256, 0, stream>>>(Y, out, gates, wc);
}